// Round 1
// baseline (321.238 us; speedup 1.0000x reference)
//
#include <hip/hip_runtime.h>
#include <math.h>

typedef unsigned long long u64;
typedef unsigned int u32;

#define NB 16
#define SL 1024
#define DIM 16
#define MDIM 16
#define KNN 8
#define CH 64    /* coors hidden */
#define NHID 32  /* node hidden */
#define LN_EPS 1e-5f
#define PST 144  /* P row stride: 4 chunks of 36 (33 units + 3 zero pad) */

__device__ __forceinline__ float silu_f(float x) {
    return x / (1.0f + __expf(-x));
}

// ---------------- init ----------------
__global__ __launch_bounds__(256) void init_kernel(
    const float* __restrict__ coords, const int* __restrict__ residues,
    const float* __restrict__ token_emb, const float* __restrict__ pos_emb,
    float* __restrict__ coordsA, float* __restrict__ featsA)
{
    const int nid = blockIdx.x * 256 + threadIdx.x;
    if (nid >= NB * SL) return;
    const int l = nid & (SL - 1);
    const int r = residues[nid];
#pragma unroll
    for (int c = 0; c < DIM; ++c)
        featsA[nid * DIM + c] = token_emb[r * DIM + c] + pos_emb[l * DIM + c];
#pragma unroll
    for (int c = 0; c < 3; ++c)
        coordsA[nid * 3 + c] = coords[nid * 3 + c];
}

// ---------------- weight transpose/pack ----------------
__global__ __launch_bounds__(256) void pack_kernel(
    const float* __restrict__ ew1, const float* __restrict__ ew2,
    const float* __restrict__ cw1,
    const float* __restrict__ nw1, const float* __restrict__ nw2,
    float* __restrict__ w1tp, float* __restrict__ w1rp, float* __restrict__ w2p,
    float* __restrict__ cw1t, float* __restrict__ nw1t, float* __restrict__ nw2t)
{
    const int stride = gridDim.x * 256;
    const int t0 = blockIdx.x * 256 + threadIdx.x;
    // w1tp[d][132][16]: o<66 -> Pi cols (input c),  o>=66 -> Pj cols (input 16+c)
    for (int idx = t0; idx < 3 * 132 * 16; idx += stride) {
        int d = idx / (132 * 16); int r = idx - d * 132 * 16; int o = r >> 4; int c = r & 15;
        int u = (o < 66) ? o : (o - 66);
        int cc = (o < 66) ? c : (16 + c);
        w1tp[idx] = ew1[(d * 33 + cc) * 66 + u];
    }
    // w1rp[d][72]: rd-row, split into 2 padded halves of 36 (rows 33..35 zero)
    for (int idx = t0; idx < 3 * 72; idx += stride) {
        int d = idx / 72; int o = idx - d * 72; int hh = o / 36; int uu = o - hh * 36;
        w1rp[idx] = (uu < 33) ? ew1[(d * 33 + 32) * 66 + hh * 33 + uu] : 0.0f;
    }
    // w2p[d][72][16]: edge w2 rows, padded halves (pad rows zero)
    for (int idx = t0; idx < 3 * 72 * 16; idx += stride) {
        int d = idx / (72 * 16); int r = idx - d * 72 * 16; int u = r >> 4; int v = r & 15;
        int hh = u / 36; int uu = u - hh * 36;
        w2p[idx] = (uu < 33) ? ew2[(d * 66 + hh * 33 + uu) * 16 + v] : 0.0f;
    }
    for (int idx = t0; idx < 3 * CH * 16; idx += stride) {
        int d = idx / (CH * 16); int r = idx - d * CH * 16; int t = r >> 4; int v = r & 15;
        cw1t[(d * CH + t) * 16 + v] = cw1[(d * 16 + v) * CH + t];
    }
    for (int idx = t0; idx < 3 * NHID * 32; idx += stride) {
        int d = idx / (NHID * 32); int r = idx - d * NHID * 32; int u = r >> 5; int c = r & 31;
        nw1t[(d * NHID + u) * 32 + c] = nw1[(d * 32 + c) * NHID + u];
    }
    for (int idx = t0; idx < 3 * 16 * 32; idx += stride) {
        int d = idx / (16 * 32); int r = idx - d * 16 * 32; int c = r >> 5; int u = r & 31;
        nw2t[(d * 16 + c) * 32 + u] = nw2[(d * 32 + u) * 16 + c];
    }
}

// ---------------- per-node edge-MLP layer-1 partials ----------------
// P[node][0..35]   = Pi units 0..32  (+eb1, pad 0)
// P[node][36..71]  = Pi units 33..65 (+eb1, pad 0)
// P[node][72..107] = Pj units 0..32  (pad 0)
// P[node][108..143]= Pj units 33..65 (pad 0)
__global__ __launch_bounds__(256) void phi_kernel(
    const int d,
    const float* __restrict__ feats,
    const float* __restrict__ w1tp, const float* __restrict__ g_eb1,
    float* __restrict__ P)
{
    __shared__ float s_wt[132 * 16];
    __shared__ float s_b[66];
    const int tid = threadIdx.x;
    for (int t = tid; t < 132 * 16; t += 256) s_wt[t] = w1tp[d * 132 * 16 + t];
    if (tid < 66) s_b[tid] = g_eb1[d * 66 + tid];
    const int p = tid >> 6;       // wave = output part (0,1: Pi halves; 2,3: Pj halves)
    const int lane = tid & 63;
    const int node = blockIdx.x * 64 + lane;
    float f[16];
    {
        const float4* fp = (const float4*)(feats + (size_t)node * DIM);
        float4 q0 = fp[0], q1 = fp[1], q2 = fp[2], q3 = fp[3];
        f[0]=q0.x; f[1]=q0.y; f[2]=q0.z; f[3]=q0.w;
        f[4]=q1.x; f[5]=q1.y; f[6]=q1.z; f[7]=q1.w;
        f[8]=q2.x; f[9]=q2.y; f[10]=q2.z; f[11]=q2.w;
        f[12]=q3.x; f[13]=q3.y; f[14]=q3.z; f[15]=q3.w;
    }
    __syncthreads();
    const int obase = p * 33;
    float res[36];
    res[33] = 0.f; res[34] = 0.f; res[35] = 0.f;
#pragma unroll 3
    for (int oo = 0; oo < 33; ++oo) {
        const float* wr = &s_wt[(obase + oo) * 16];   // wave-uniform -> broadcast
        float a0 = (p < 2) ? s_b[obase + oo] : 0.0f;
        float a1 = 0.f, a2 = 0.f, a3 = 0.f;
#pragma unroll
        for (int c = 0; c < 16; c += 4) {
            a0 = fmaf(f[c + 0], wr[c + 0], a0);
            a1 = fmaf(f[c + 1], wr[c + 1], a1);
            a2 = fmaf(f[c + 2], wr[c + 2], a2);
            a3 = fmaf(f[c + 3], wr[c + 3], a3);
        }
        res[oo] = (a0 + a1) + (a2 + a3);
    }
    float4* outp = (float4*)(P + (size_t)node * PST + p * 36);
#pragma unroll
    for (int q = 0; q < 9; ++q)
        outp[q] = make_float4(res[4 * q + 0], res[4 * q + 1], res[4 * q + 2], res[4 * q + 3]);
}

// ---------------- kNN (unchanged) ----------------
__device__ __forceinline__ void merge8(u32* a, const u32* bb) {
    u32 c[8];
#pragma unroll
    for (int t = 0; t < 8; ++t) c[t] = min(a[t], bb[7 - t]);
#define MCAS(x, y) { u32 mn = min(c[x], c[y]); u32 mx = max(c[x], c[y]); c[x] = mn; c[y] = mx; }
    MCAS(0, 4) MCAS(1, 5) MCAS(2, 6) MCAS(3, 7)
    MCAS(0, 2) MCAS(1, 3) MCAS(4, 6) MCAS(5, 7)
    MCAS(0, 1) MCAS(2, 3) MCAS(4, 5) MCAS(6, 7)
#undef MCAS
#pragma unroll
    for (int t = 0; t < 8; ++t) a[t] = c[t];
}

__global__ __launch_bounds__(1024) void knn_kernel(
    const float* __restrict__ coords, const int* __restrict__ lengths,
    int* __restrict__ idxbuf)
{
    __shared__ float s_cand[SL * 3];        // 12 KB
    __shared__ u32 lists[16][64][9];        // 36 KB, pad 9 vs bank conflicts
    const int tid = threadIdx.x;
    const int b = blockIdx.x >> 4;
    const int i0 = (blockIdx.x & 15) << 6;
    const int len = lengths[b];
    const float* cb = coords + (size_t)b * SL * 3;
    for (int idx = tid; idx < SL * 3; idx += 1024) s_cand[idx] = cb[idx];
    __syncthreads();

    const int wv = tid >> 6;     // candidate slice 0..15
    const int lane = tid & 63;   // query within group
    const int i = i0 + lane;
    const bool mi = i < len;
    const float xi = s_cand[i * 3 + 0], yi = s_cand[i * 3 + 1], zi = s_cand[i * 3 + 2];

    u32 lst[8];
#pragma unroll
    for (int t = 0; t < 8; ++t) lst[t] = 0xFFFFFFFFu;

    const int jbase = wv << 6;
#pragma unroll 4
    for (int jj = 0; jj < 64; ++jj) {
        const int j = jbase + jj;
        const float xj = s_cand[j * 3 + 0], yj = s_cand[j * 3 + 1], zj = s_cand[j * 3 + 2];
        const float dx = xi - xj, dy = yi - yj, dz = zi - zj;
        const float dist = dx * dx + dy * dy + dz * dz;
        const bool pm = mi && (j < len);
        float v = pm ? dist : 1e5f;
        v = (pm && (j - i == 1 || i - j == 1)) ? 0.0f : v;
        v = (j == i) ? -1.0f : v;
        u32 bits = __float_as_uint(v);
        bits ^= (u32)((int)bits >> 31) | 0x80000000u;
        const u32 key = (bits & 0xFFFFFC00u) | (u32)j;
#pragma unroll
        for (int p = 7; p >= 1; --p)
            lst[p] = (key < lst[p]) ? ((key < lst[p - 1]) ? lst[p - 1] : key) : lst[p];
        lst[0] = min(key, lst[0]);
    }

#pragma unroll
    for (int t = 0; t < 8; ++t) lists[wv][lane][t] = lst[t];
    __syncthreads();

    if (tid < 512) {
        const int p = tid >> 6, q = tid & 63;
        u32 a[8], bb[8];
#pragma unroll
        for (int t = 0; t < 8; ++t) { a[t] = lists[2 * p][q][t]; bb[t] = lists[2 * p + 1][q][t]; }
        merge8(a, bb);
#pragma unroll
        for (int t = 0; t < 8; ++t) lists[2 * p][q][t] = a[t];
    }
    __syncthreads();
    if (tid < 256) {
        const int p = tid >> 6, q = tid & 63;
        u32 a[8], bb[8];
#pragma unroll
        for (int t = 0; t < 8; ++t) { a[t] = lists[4 * p][q][t]; bb[t] = lists[4 * p + 2][q][t]; }
        merge8(a, bb);
#pragma unroll
        for (int t = 0; t < 8; ++t) lists[4 * p][q][t] = a[t];
    }
    __syncthreads();
    if (tid < 128) {
        const int p = tid >> 6, q = tid & 63;
        u32 a[8], bb[8];
#pragma unroll
        for (int t = 0; t < 8; ++t) { a[t] = lists[8 * p][q][t]; bb[t] = lists[8 * p + 4][q][t]; }
        merge8(a, bb);
#pragma unroll
        for (int t = 0; t < 8; ++t) lists[8 * p][q][t] = a[t];
    }
    __syncthreads();
    if (tid < 64) {
        const int q = tid;
        u32 a[8], bb[8];
#pragma unroll
        for (int t = 0; t < 8; ++t) { a[t] = lists[0][q][t]; bb[t] = lists[8][q][t]; }
        merge8(a, bb);
        const size_t node = (size_t)b * SL + i0 + q;
        int4 r0 = make_int4((int)(a[0] & 1023u), (int)(a[1] & 1023u), (int)(a[2] & 1023u), (int)(a[3] & 1023u));
        int4 r1 = make_int4((int)(a[4] & 1023u), (int)(a[5] & 1023u), (int)(a[6] & 1023u), (int)(a[7] & 1023u));
        ((int4*)idxbuf)[node * 2 + 0] = r0;
        ((int4*)idxbuf)[node * 2 + 1] = r1;
    }
}

// ---------------- EGNN layer: edge MLP layer-1 replaced by per-node partials ----------------
__global__ __launch_bounds__(256, 4) void layer_kernel(
    const int d,
    const float* __restrict__ coordsIn, float* __restrict__ coordsOut,
    const float* __restrict__ featsIn, float* __restrict__ featsOut,
    const float* __restrict__ Pbuf,
    const int* __restrict__ idxbuf, const int* __restrict__ lengths,
    const float* __restrict__ w1rp, const float* __restrict__ w2p,
    const float* __restrict__ g_eb2,
    const float* __restrict__ cw1t, const float* __restrict__ g_cb1,
    const float* __restrict__ g_cw2, const float* __restrict__ g_cb2,
    const float* __restrict__ g_lng, const float* __restrict__ g_lnb,
    const float* __restrict__ nw1t, const float* __restrict__ g_nb1,
    const float* __restrict__ nw2t, const float* __restrict__ g_nb2)
{
    __shared__ float s_w2e[72 * 16];                 // 4608 B
    __shared__ float s_w1r[72];
    __shared__ float s_cw1[CH * 16];                 // 4096 B
    __shared__ float s_cw2v[CH];
    __shared__ float s_nw1[NHID * 36];               // padded rows: bank spread
    __shared__ float s_nw2[16 * 36];
    __shared__ float s_eb2[16], s_cb1[CH];
    __shared__ float s_lng[16], s_lnb[16], s_nb1[32], s_nb2[16];
    __shared__ float s_cb2v;
    __shared__ __align__(16) float s_ex[2 * 64 * 20];  // wave-pair exchange, stride 20

    const int tid = threadIdx.x;
    for (int t = tid; t < 72 * 16; t += 256) s_w2e[t] = w2p[d * 72 * 16 + t];
    for (int t = tid; t < CH * 16; t += 256) s_cw1[t] = cw1t[d * CH * 16 + t];
    for (int t = tid; t < NHID * 32; t += 256) s_nw1[(t >> 5) * 36 + (t & 31)] = nw1t[d * NHID * 32 + t];
    for (int t = tid; t < 16 * 32; t += 256) s_nw2[(t >> 5) * 36 + (t & 31)] = nw2t[d * 16 * 32 + t];
    if (tid < 72) s_w1r[tid] = w1rp[d * 72 + tid];
    if (tid < CH) { s_cw2v[tid] = g_cw2[d * CH + tid]; s_cb1[tid] = g_cb1[d * CH + tid]; }
    if (tid < 16) {
        s_eb2[tid] = g_eb2[d * 16 + tid];
        s_lng[tid] = g_lng[d * 16 + tid];
        s_lnb[tid] = g_lnb[d * 16 + tid];
        s_nb2[tid] = g_nb2[d * 16 + tid];
    }
    if (tid < 32) s_nb1[tid] = g_nb1[d * 32 + tid];
    if (tid == 0) s_cb2v = g_cb2[d];

    const int wvid = tid >> 6;
    const int h = wvid & 1;          // wave-uniform half
    const int p = wvid >> 1;         // wave pair
    const int lane = tid & 63;
    const int e = blockIdx.x * 128 + p * 64 + lane;
    const int n = e >> 3;
    const int b = n >> 10;
    const int i = n & (SL - 1);
    const int k = lane & 7;
    const int len = lengths[b];
    const int j = idxbuf[e];
    const bool em = (i < len) && (j < len);

    // ---- inputs ----
    float fi[16];
    {
        const float4* pp = (const float4*)(featsIn + (size_t)n * DIM);
        float4 a = pp[0], c2 = pp[1], c3 = pp[2], c4 = pp[3];
        fi[0]=a.x; fi[1]=a.y; fi[2]=a.z; fi[3]=a.w;
        fi[4]=c2.x; fi[5]=c2.y; fi[6]=c2.z; fi[7]=c2.w;
        fi[8]=c3.x; fi[9]=c3.y; fi[10]=c3.z; fi[11]=c3.w;
        fi[12]=c4.x; fi[13]=c4.y; fi[14]=c4.z; fi[15]=c4.w;
    }
    float ci[3], rel[3];
    {
        const float* cp = coordsIn + (size_t)n * 3;
        const float* cq = coordsIn + ((size_t)b * SL + j) * 3;
        ci[0] = cp[0]; ci[1] = cp[1]; ci[2] = cp[2];
        rel[0] = ci[0] - cq[0]; rel[1] = ci[1] - cq[1]; rel[2] = ci[2] - cq[2];
    }
    const float rd = fmaf(rel[0], rel[0], fmaf(rel[1], rel[1], rel[2] * rel[2]));

    // partial prefetch of P before the barrier (independent of LDS)
    const int ub = h * 36;
    const float* PiP = Pbuf + (size_t)n * PST + ub;
    const float* PjP = Pbuf + ((size_t)b * SL + j) * PST + 72 + ub;
    float4 pa = *(const float4*)PiP;
    float4 pb = *(const float4*)PjP;

    __syncthreads();   // weights staged

    // ---- edge MLP layer-1 via precomputed partials; layer-2 accumulate ----
    float macc[16];
#pragma unroll
    for (int v = 0; v < 16; ++v) macc[v] = h ? 0.0f : s_eb2[v];
#pragma unroll
    for (int c4 = 0; c4 < 9; ++c4) {
        float4 na, nb;
        if (c4 < 8) {
            na = *(const float4*)(PiP + 4 * (c4 + 1));
            nb = *(const float4*)(PjP + 4 * (c4 + 1));
        }
        const int u0 = ub + c4 * 4;
        const float hu0 = silu_f(fmaf(rd, s_w1r[u0 + 0], pa.x + pb.x));
        const float hu1 = silu_f(fmaf(rd, s_w1r[u0 + 1], pa.y + pb.y));
        const float hu2 = silu_f(fmaf(rd, s_w1r[u0 + 2], pa.z + pb.z));
        const float hu3 = silu_f(fmaf(rd, s_w1r[u0 + 3], pa.w + pb.w));
        const float* w2r = &s_w2e[u0 * 16];
#pragma unroll
        for (int v = 0; v < 16; ++v) {
            float m0 = fmaf(hu0, w2r[v], macc[v]);
            float m1 = fmaf(hu1, w2r[16 + v], m0);
            float m2 = fmaf(hu2, w2r[32 + v], m1);
            macc[v] = fmaf(hu3, w2r[48 + v], m2);
        }
        if (c4 < 8) { pa = na; pb = nb; }
    }

    // ---- combine halves via LDS (stride-20, 16B-aligned) ----
    float4* exq = (float4*)&s_ex[((p << 6) + lane) * 20];
    if (h) {
        exq[0] = make_float4(macc[0], macc[1], macc[2], macc[3]);
        exq[1] = make_float4(macc[4], macc[5], macc[6], macc[7]);
        exq[2] = make_float4(macc[8], macc[9], macc[10], macc[11]);
        exq[3] = make_float4(macc[12], macc[13], macc[14], macc[15]);
    }
    __syncthreads();
    float mm[16];
    if (!h) {
        float4 e0 = exq[0], e1 = exq[1], e2 = exq[2], e3 = exq[3];
        macc[0]+=e0.x; macc[1]+=e0.y; macc[2]+=e0.z; macc[3]+=e0.w;
        macc[4]+=e1.x; macc[5]+=e1.y; macc[6]+=e1.z; macc[7]+=e1.w;
        macc[8]+=e2.x; macc[9]+=e2.y; macc[10]+=e2.z; macc[11]+=e2.w;
        macc[12]+=e3.x; macc[13]+=e3.y; macc[14]+=e3.z; macc[15]+=e3.w;
#pragma unroll
        for (int v = 0; v < 16; ++v) mm[v] = silu_f(macc[v]);
        exq[0] = make_float4(mm[0], mm[1], mm[2], mm[3]);
        exq[1] = make_float4(mm[4], mm[5], mm[6], mm[7]);
        exq[2] = make_float4(mm[8], mm[9], mm[10], mm[11]);
        exq[3] = make_float4(mm[12], mm[13], mm[14], mm[15]);
    }
    __syncthreads();
    if (h) {
        float4 e0 = exq[0], e1 = exq[1], e2 = exq[2], e3 = exq[3];
        mm[0]=e0.x; mm[1]=e0.y; mm[2]=e0.z; mm[3]=e0.w;
        mm[4]=e1.x; mm[5]=e1.y; mm[6]=e1.z; mm[7]=e1.w;
        mm[8]=e2.x; mm[9]=e2.y; mm[10]=e2.z; mm[11]=e2.w;
        mm[12]=e3.x; mm[13]=e3.y; mm[14]=e3.z; mm[15]=e3.w;
    }

    // ---- coors MLP, t-range [h*32, h*32+32) ----
    const int tb = h * 32;
    float wa = 0.f;
#pragma unroll 4
    for (int tt = 0; tt < 32; ++tt) {
        const float* cr = &s_cw1[(tb + tt) * 16];
        float a0 = s_cb1[tb + tt], a1 = 0.f;
#pragma unroll
        for (int v = 0; v < 16; v += 2) {
            a0 = fmaf(mm[v], cr[v], a0);
            a1 = fmaf(mm[v + 1], cr[v + 1], a1);
        }
        wa = fmaf(silu_f(a0 + a1), s_cw2v[tb + tt], wa);
    }
    s_ex[((p << 6) + lane) * 20 + 16 + h] = wa;
    __syncthreads();
    const float wao = s_ex[((p << 6) + lane) * 20 + 17 - h];
    const float we = em ? (wa + wao + s_cb2v) : 0.f;

    // ---- coordinate update: reduce over 8 edges of node ----
    float wr0 = we * rel[0], wr1 = we * rel[1], wr2 = we * rel[2];
#pragma unroll
    for (int s = 1; s < 8; s <<= 1) {
        wr0 += __shfl_xor(wr0, s, 64);
        wr1 += __shfl_xor(wr1, s, 64);
        wr2 += __shfl_xor(wr2, s, 64);
    }
    if (!h && k == 0) {
        coordsOut[(size_t)n * 3 + 0] = ci[0] + wr0;
        coordsOut[(size_t)n * 3 + 1] = ci[1] + wr1;
        coordsOut[(size_t)n * 3 + 2] = ci[2] + wr2;
    }

    // ---- m_i ----
    float mi_[16];
#pragma unroll
    for (int v = 0; v < 16; ++v) mi_[v] = em ? mm[v] : 0.f;
#pragma unroll
    for (int s = 1; s < 8; s <<= 1) {
#pragma unroll
        for (int v = 0; v < 16; ++v) mi_[v] += __shfl_xor(mi_[v], s, 64);
    }

    // ---- LayerNorm ----
    float mu = 0.f;
#pragma unroll
    for (int c = 0; c < 16; ++c) mu += fi[c];
    mu *= 0.0625f;
    float var = 0.f;
#pragma unroll
    for (int c = 0; c < 16; ++c) { const float dd = fi[c] - mu; var = fmaf(dd, dd, var); }
    var *= 0.0625f;
    const float rs = rsqrtf(var + LN_EPS);
    float nn[16];
#pragma unroll
    for (int c = 0; c < 16; ++c) nn[c] = fmaf((fi[c] - mu) * rs, s_lng[c], s_lnb[c]);

    // ---- node MLP hidden: lane k owns units k*4..k*4+3 (fully deduped) ----
    float nh[4];
#pragma unroll
    for (int q = 0; q < 4; ++q) {
        const int u = k * 4 + q;
        const float* nr = &s_nw1[u * 36];
        float a0 = s_nb1[u], a1 = 0.f;
#pragma unroll
        for (int c = 0; c < 16; c += 2) {
            a0 = fmaf(nn[c], nr[c], a0);
            a1 = fmaf(nn[c + 1], nr[c + 1], a1);
        }
#pragma unroll
        for (int v = 0; v < 16; v += 2) {
            a0 = fmaf(mi_[v], nr[16 + v], a0);
            a1 = fmaf(mi_[v + 1], nr[16 + v + 1], a1);
        }
        nh[q] = silu_f(a0 + a1);
    }

    // ---- node MLP out: lane k computes channels 2k, 2k+1 via shfl gather ----
    const int c0 = 2 * k, c1 = 2 * k + 1;
    const float* w2a = &s_nw2[c0 * 36];
    const float* w2b = &s_nw2[c1 * 36];
    float o0 = s_nb2[c0], o1 = s_nb2[c1];
    const int lbase = lane & ~7;
#pragma unroll
    for (int u = 0; u < 32; ++u) {
        const float v = __shfl(nh[u & 3], lbase + (u >> 2), 64);
        o0 = fmaf(v, w2a[u], o0);
        o1 = fmaf(v, w2b[u], o1);
    }
    if (!h) {
        ((float2*)featsOut)[(size_t)n * 8 + k] = make_float2(fi[c0] + o0, fi[c1] + o1);
    }
}

// ---------------- final projection ----------------
__global__ __launch_bounds__(256) void final_kernel(
    const float* __restrict__ feats, const float* __restrict__ fw,
    const float* __restrict__ fb, float* __restrict__ out)
{
    const int nid = blockIdx.x * 256 + threadIdx.x;
    if (nid >= NB * SL) return;
    float f[DIM];
#pragma unroll
    for (int c = 0; c < DIM; ++c) f[c] = feats[nid * DIM + c];
#pragma unroll
    for (int o = 0; o < 3; ++o) {
        float acc = fb[o];
#pragma unroll
        for (int c = 0; c < DIM; ++c) acc = fmaf(f[c], fw[c * 3 + o], acc);
        out[nid * 3 + o] = acc;
    }
}

extern "C" void kernel_launch(void* const* d_in, const int* in_sizes, int n_in,
                              void* d_out, int out_size, void* d_ws, size_t ws_size,
                              hipStream_t stream) {
    const float* coords    = (const float*)d_in[0];
    const int*   residues  = (const int*)d_in[1];
    const int*   lengths   = (const int*)d_in[2];
    const float* token_emb = (const float*)d_in[3];
    const float* pos_emb   = (const float*)d_in[4];
    const float* ew1 = (const float*)d_in[5];
    const float* eb1 = (const float*)d_in[6];
    const float* ew2 = (const float*)d_in[7];
    const float* eb2 = (const float*)d_in[8];
    const float* cw1 = (const float*)d_in[9];
    const float* cb1 = (const float*)d_in[10];
    const float* cw2 = (const float*)d_in[11];
    const float* cb2 = (const float*)d_in[12];
    const float* lng = (const float*)d_in[13];
    const float* lnb = (const float*)d_in[14];
    const float* nw1 = (const float*)d_in[15];
    const float* nb1 = (const float*)d_in[16];
    const float* nw2 = (const float*)d_in[17];
    const float* nb2 = (const float*)d_in[18];
    const float* fw  = (const float*)d_in[19];
    const float* fb  = (const float*)d_in[20];

    float* ws = (float*)d_ws;
    float* coordsA = ws;
    float* coordsB = coordsA + NB * SL * 3;
    float* featsA  = coordsB + NB * SL * 3;
    float* featsB  = featsA + NB * SL * DIM;
    int*   idxbuf  = (int*)(featsB + NB * SL * DIM);
    float* w1tp = (float*)(idxbuf + NB * SL * KNN);     // 3*132*16
    float* w1rp = w1tp + 3 * 132 * 16;                  // 3*72
    float* w2p  = w1rp + 3 * 72;                        // 3*72*16
    float* cw1t = w2p + 3 * 72 * 16;                    // 3*64*16
    float* nw1t = cw1t + 3 * CH * 16;                   // 3*32*32
    float* nw2t = nw1t + 3 * NHID * 32;                 // 3*16*32
    float* Pbuf = nw2t + 3 * 16 * 32;                   // 16384*144

    pack_kernel<<<32, 256, 0, stream>>>(ew1, ew2, cw1, nw1, nw2, w1tp, w1rp, w2p, cw1t, nw1t, nw2t);
    init_kernel<<<NB * SL / 256, 256, 0, stream>>>(coords, residues, token_emb, pos_emb, coordsA, featsA);

    float* cIn = coordsA; float* cOut = coordsB;
    float* fIn = featsA;  float* fOut = featsB;
    for (int d = 0; d < 3; ++d) {
        knn_kernel<<<NB * SL / 64, 1024, 0, stream>>>(cIn, lengths, idxbuf);
        phi_kernel<<<NB * SL / 64, 256, 0, stream>>>(d, fIn, w1tp, eb1, Pbuf);
        layer_kernel<<<NB * SL * KNN / 128, 256, 0, stream>>>(d, cIn, cOut, fIn, fOut, Pbuf, idxbuf, lengths,
            w1rp, w2p, eb2, cw1t, cb1, cw2, cb2, lng, lnb, nw1t, nb1, nw2t, nb2);
        float* t;
        t = cIn; cIn = cOut; cOut = t;
        t = fIn; fIn = fOut; fOut = t;
    }

    final_kernel<<<NB * SL / 256, 256, 0, stream>>>(fIn, fw, fb, (float*)d_out);
}

// Round 2
// 293.229 us; speedup vs baseline: 1.0955x; 1.0955x over previous
//
#include <hip/hip_runtime.h>
#include <math.h>

typedef unsigned long long u64;
typedef unsigned int u32;

#define NB 16
#define SL 1024
#define DIM 16
#define MDIM 16
#define KNN 8
#define CH 64    /* coors hidden */
#define NHID 32  /* node hidden */
#define LN_EPS 1e-5f
#define PST 144  /* P row stride: 4 chunks of 36 (33 units + 3 zero pad) */

__device__ __forceinline__ float silu_f(float x) {
    return x / (1.0f + __expf(-x));
}

// ---------------- init: feats/coords copy + fused phi for layer 0 ----------------
// 4 threads per node; thread part p computes P chunk p (36 cols).
__global__ __launch_bounds__(256) void init_kernel(
    const float* __restrict__ coords, const int* __restrict__ residues,
    const float* __restrict__ token_emb, const float* __restrict__ pos_emb,
    const float* __restrict__ w1tp, const float* __restrict__ g_eb1,
    float* __restrict__ coordsA, float* __restrict__ featsA,
    float* __restrict__ Pout)
{
    const int t = blockIdx.x * 256 + threadIdx.x;
    const int node = t >> 2;
    const int part = t & 3;
    const int l = node & (SL - 1);
    const int r = residues[node];
    float f[16];
    {
        const float4* te = (const float4*)(token_emb + (size_t)r * DIM);
        const float4* pe = (const float4*)(pos_emb + (size_t)l * DIM);
#pragma unroll
        for (int q = 0; q < 4; ++q) {
            float4 a = te[q], b4 = pe[q];
            f[4*q+0] = a.x + b4.x; f[4*q+1] = a.y + b4.y;
            f[4*q+2] = a.z + b4.z; f[4*q+3] = a.w + b4.w;
        }
    }
    if (part == 0) {
        float4* fo = (float4*)(featsA + (size_t)node * DIM);
#pragma unroll
        for (int q = 0; q < 4; ++q)
            fo[q] = make_float4(f[4*q], f[4*q+1], f[4*q+2], f[4*q+3]);
        coordsA[node * 3 + 0] = coords[node * 3 + 0];
        coordsA[node * 3 + 1] = coords[node * 3 + 1];
        coordsA[node * 3 + 2] = coords[node * 3 + 2];
    }
    const int ubase = (part & 1) * 33;
    const int wbase = (part < 2) ? 0 : 66;
    float res[36];
    res[33] = 0.f; res[34] = 0.f; res[35] = 0.f;
#pragma unroll
    for (int oo = 0; oo < 33; ++oo) {     // FULL unroll: res[] stays in registers
        const int u = ubase + oo;
        const float* wr = w1tp + (wbase + u) * 16;
        float a0 = (part < 2) ? g_eb1[u] : 0.0f;
        float a1 = 0.f, a2 = 0.f, a3 = 0.f;
#pragma unroll
        for (int c = 0; c < 16; c += 4) {
            a0 = fmaf(f[c + 0], wr[c + 0], a0);
            a1 = fmaf(f[c + 1], wr[c + 1], a1);
            a2 = fmaf(f[c + 2], wr[c + 2], a2);
            a3 = fmaf(f[c + 3], wr[c + 3], a3);
        }
        res[oo] = (a0 + a1) + (a2 + a3);
    }
    float4* op = (float4*)(Pout + (size_t)node * PST + part * 36);
#pragma unroll
    for (int q = 0; q < 9; ++q)
        op[q] = make_float4(res[4*q], res[4*q+1], res[4*q+2], res[4*q+3]);
}

// ---------------- weight transpose/pack ----------------
__global__ __launch_bounds__(256) void pack_kernel(
    const float* __restrict__ ew1, const float* __restrict__ ew2,
    const float* __restrict__ cw1,
    const float* __restrict__ nw1, const float* __restrict__ nw2,
    float* __restrict__ w1tp, float* __restrict__ w1rp, float* __restrict__ w2p,
    float* __restrict__ cw1t, float* __restrict__ nw1t, float* __restrict__ nw2t)
{
    const int stride = gridDim.x * 256;
    const int t0 = blockIdx.x * 256 + threadIdx.x;
    // w1tp[d][132][16]: o<66 -> Pi cols (input c),  o>=66 -> Pj cols (input 16+c)
    for (int idx = t0; idx < 3 * 132 * 16; idx += stride) {
        int d = idx / (132 * 16); int r = idx - d * 132 * 16; int o = r >> 4; int c = r & 15;
        int u = (o < 66) ? o : (o - 66);
        int cc = (o < 66) ? c : (16 + c);
        w1tp[idx] = ew1[(d * 33 + cc) * 66 + u];
    }
    // w1rp[d][72]: rd-row, split into 2 padded halves of 36 (rows 33..35 zero)
    for (int idx = t0; idx < 3 * 72; idx += stride) {
        int d = idx / 72; int o = idx - d * 72; int hh = o / 36; int uu = o - hh * 36;
        w1rp[idx] = (uu < 33) ? ew1[(d * 33 + 32) * 66 + hh * 33 + uu] : 0.0f;
    }
    // w2p[d][72][16]: edge w2 rows, padded halves (pad rows zero)
    for (int idx = t0; idx < 3 * 72 * 16; idx += stride) {
        int d = idx / (72 * 16); int r = idx - d * 72 * 16; int u = r >> 4; int v = r & 15;
        int hh = u / 36; int uu = u - hh * 36;
        w2p[idx] = (uu < 33) ? ew2[(d * 66 + hh * 33 + uu) * 16 + v] : 0.0f;
    }
    for (int idx = t0; idx < 3 * CH * 16; idx += stride) {
        int d = idx / (CH * 16); int r = idx - d * CH * 16; int t = r >> 4; int v = r & 15;
        cw1t[(d * CH + t) * 16 + v] = cw1[(d * 16 + v) * CH + t];
    }
    for (int idx = t0; idx < 3 * NHID * 32; idx += stride) {
        int d = idx / (NHID * 32); int r = idx - d * NHID * 32; int u = r >> 5; int c = r & 31;
        nw1t[(d * NHID + u) * 32 + c] = nw1[(d * 32 + c) * NHID + u];
    }
    for (int idx = t0; idx < 3 * 16 * 32; idx += stride) {
        int d = idx / (16 * 32); int r = idx - d * 16 * 32; int c = r >> 5; int u = r & 31;
        nw2t[(d * 16 + c) * 32 + u] = nw2[(d * 32 + u) * 16 + c];
    }
}

// ---------------- kNN: float4-staged candidates, broadcast b128 reads ----------------
__device__ __forceinline__ void merge8(u32* a, const u32* bb) {
    u32 c[8];
#pragma unroll
    for (int t = 0; t < 8; ++t) c[t] = min(a[t], bb[7 - t]);
#define MCAS(x, y) { u32 mn = min(c[x], c[y]); u32 mx = max(c[x], c[y]); c[x] = mn; c[y] = mx; }
    MCAS(0, 4) MCAS(1, 5) MCAS(2, 6) MCAS(3, 7)
    MCAS(0, 2) MCAS(1, 3) MCAS(4, 6) MCAS(5, 7)
    MCAS(0, 1) MCAS(2, 3) MCAS(4, 5) MCAS(6, 7)
#undef MCAS
#pragma unroll
    for (int t = 0; t < 8; ++t) a[t] = c[t];
}

__global__ __launch_bounds__(1024) void knn_kernel(
    const float* __restrict__ coords, const int* __restrict__ lengths,
    int* __restrict__ idxbuf)
{
    __shared__ __align__(16) float4 s_cand[SL];   // 16 KB (padded xyz)
    __shared__ u32 lists[16][64][9];              // 36 KB, pad 9 vs bank conflicts
    const int tid = threadIdx.x;
    const int b = blockIdx.x >> 4;
    const int i0 = (blockIdx.x & 15) << 6;
    const int len = lengths[b];
    const float* cb = coords + (size_t)b * SL * 3;
    for (int idx = tid; idx < SL; idx += 1024) {
        const float* cp = cb + idx * 3;
        s_cand[idx] = make_float4(cp[0], cp[1], cp[2], 0.0f);
    }
    __syncthreads();

    const int wv = tid >> 6;     // candidate slice 0..15
    const int lane = tid & 63;   // query within group
    const int i = i0 + lane;
    const bool mi = i < len;
    const float4 qi = s_cand[i];
    const float xi = qi.x, yi = qi.y, zi = qi.z;

    u32 lst[8];
#pragma unroll
    for (int t = 0; t < 8; ++t) lst[t] = 0xFFFFFFFFu;

    const int jbase = wv << 6;
#pragma unroll 4
    for (int jj = 0; jj < 64; ++jj) {
        const int j = jbase + jj;
        const float4 cj = s_cand[j];   // wave-uniform addr -> LDS broadcast
        const float dx = xi - cj.x, dy = yi - cj.y, dz = zi - cj.z;
        const float dist = dx * dx + dy * dy + dz * dz;
        const bool pm = mi && (j < len);
        float v = pm ? dist : 1e5f;
        v = (pm && (j - i == 1 || i - j == 1)) ? 0.0f : v;
        v = (j == i) ? -1.0f : v;
        u32 bits = __float_as_uint(v);
        bits ^= (u32)((int)bits >> 31) | 0x80000000u;
        const u32 key = (bits & 0xFFFFFC00u) | (u32)j;
#pragma unroll
        for (int p = 7; p >= 1; --p)
            lst[p] = (key < lst[p]) ? ((key < lst[p - 1]) ? lst[p - 1] : key) : lst[p];
        lst[0] = min(key, lst[0]);
    }

#pragma unroll
    for (int t = 0; t < 8; ++t) lists[wv][lane][t] = lst[t];
    __syncthreads();

    if (tid < 512) {
        const int p = tid >> 6, q = tid & 63;
        u32 a[8], bb[8];
#pragma unroll
        for (int t = 0; t < 8; ++t) { a[t] = lists[2 * p][q][t]; bb[t] = lists[2 * p + 1][q][t]; }
        merge8(a, bb);
#pragma unroll
        for (int t = 0; t < 8; ++t) lists[2 * p][q][t] = a[t];
    }
    __syncthreads();
    if (tid < 256) {
        const int p = tid >> 6, q = tid & 63;
        u32 a[8], bb[8];
#pragma unroll
        for (int t = 0; t < 8; ++t) { a[t] = lists[4 * p][q][t]; bb[t] = lists[4 * p + 2][q][t]; }
        merge8(a, bb);
#pragma unroll
        for (int t = 0; t < 8; ++t) lists[4 * p][q][t] = a[t];
    }
    __syncthreads();
    if (tid < 128) {
        const int p = tid >> 6, q = tid & 63;
        u32 a[8], bb[8];
#pragma unroll
        for (int t = 0; t < 8; ++t) { a[t] = lists[8 * p][q][t]; bb[t] = lists[8 * p + 4][q][t]; }
        merge8(a, bb);
#pragma unroll
        for (int t = 0; t < 8; ++t) lists[8 * p][q][t] = a[t];
    }
    __syncthreads();
    if (tid < 64) {
        const int q = tid;
        u32 a[8], bb[8];
#pragma unroll
        for (int t = 0; t < 8; ++t) { a[t] = lists[0][q][t]; bb[t] = lists[8][q][t]; }
        merge8(a, bb);
        const size_t node = (size_t)b * SL + i0 + q;
        int4 r0 = make_int4((int)(a[0] & 1023u), (int)(a[1] & 1023u), (int)(a[2] & 1023u), (int)(a[3] & 1023u));
        int4 r1 = make_int4((int)(a[4] & 1023u), (int)(a[5] & 1023u), (int)(a[6] & 1023u), (int)(a[7] & 1023u));
        ((int4*)idxbuf)[node * 2 + 0] = r0;
        ((int4*)idxbuf)[node * 2 + 1] = r1;
    }
}

// ---------------- EGNN layer: factored edge MLP + fused next-layer phi epilogue ----------------
__global__ __launch_bounds__(256, 4) void layer_kernel(
    const int d,
    const float* __restrict__ coordsIn, float* __restrict__ coordsOut,
    const float* __restrict__ featsIn, float* __restrict__ featsOut,
    const float* __restrict__ Pbuf,
    const int* __restrict__ idxbuf, const int* __restrict__ lengths,
    const float* __restrict__ w1rp, const float* __restrict__ w2p,
    const float* __restrict__ g_eb2,
    const float* __restrict__ cw1t, const float* __restrict__ g_cb1,
    const float* __restrict__ g_cw2, const float* __restrict__ g_cb2,
    const float* __restrict__ g_lng, const float* __restrict__ g_lnb,
    const float* __restrict__ nw1t, const float* __restrict__ g_nb1,
    const float* __restrict__ nw2t, const float* __restrict__ g_nb2,
    const float* __restrict__ w1tp_all, const float* __restrict__ g_eb1,
    float* __restrict__ PbufOut)
{
    __shared__ float s_w2e[72 * 16];                 // 4608 B
    __shared__ float s_w1r[72];
    __shared__ float s_cw1[CH * 16];                 // 4096 B
    __shared__ float s_cw2v[CH];
    __shared__ float s_nw1[NHID * 36];               // padded rows: bank spread
    __shared__ float s_nw2[16 * 36];
    __shared__ float s_eb2[16], s_cb1[CH];
    __shared__ float s_lng[16], s_lnb[16], s_nb1[32], s_nb2[16];
    __shared__ float s_cb2v;
    __shared__ __align__(16) float s_ex[2 * 64 * 20];   // wave-pair exchange, 10240 B
    __shared__ __align__(16) float s_wphi[132 * 20];    // next-layer w1, stride 20, 10560 B
    __shared__ float s_eb1n[66];
    __shared__ __align__(16) float s_nf[16 * 20];       // new feats rows, 1280 B

    const int tid = threadIdx.x;
    for (int t = tid; t < 72 * 16; t += 256) s_w2e[t] = w2p[d * 72 * 16 + t];
    for (int t = tid; t < CH * 16; t += 256) s_cw1[t] = cw1t[d * CH * 16 + t];
    for (int t = tid; t < NHID * 32; t += 256) s_nw1[(t >> 5) * 36 + (t & 31)] = nw1t[d * NHID * 32 + t];
    for (int t = tid; t < 16 * 32; t += 256) s_nw2[(t >> 5) * 36 + (t & 31)] = nw2t[d * 16 * 32 + t];
    if (d < 2) {
        for (int t = tid; t < 132 * 16; t += 256)
            s_wphi[(t >> 4) * 20 + (t & 15)] = w1tp_all[(d + 1) * 132 * 16 + t];
        if (tid < 66) s_eb1n[tid] = g_eb1[(d + 1) * 66 + tid];
    }
    if (tid < 72) s_w1r[tid] = w1rp[d * 72 + tid];
    if (tid < CH) { s_cw2v[tid] = g_cw2[d * CH + tid]; s_cb1[tid] = g_cb1[d * CH + tid]; }
    if (tid < 16) {
        s_eb2[tid] = g_eb2[d * 16 + tid];
        s_lng[tid] = g_lng[d * 16 + tid];
        s_lnb[tid] = g_lnb[d * 16 + tid];
        s_nb2[tid] = g_nb2[d * 16 + tid];
    }
    if (tid < 32) s_nb1[tid] = g_nb1[d * 32 + tid];
    if (tid == 0) s_cb2v = g_cb2[d];

    const int wvid = tid >> 6;
    const int h = wvid & 1;          // wave-uniform half
    const int p = wvid >> 1;         // wave pair
    const int lane = tid & 63;
    const int e = blockIdx.x * 128 + p * 64 + lane;
    const int n = e >> 3;
    const int b = n >> 10;
    const int i = n & (SL - 1);
    const int k = lane & 7;
    const int len = lengths[b];
    const int j = idxbuf[e];
    const bool em = (i < len) && (j < len);

    // ---- inputs ----
    float fi[16];
    {
        const float4* pp = (const float4*)(featsIn + (size_t)n * DIM);
        float4 a = pp[0], c2 = pp[1], c3 = pp[2], c4 = pp[3];
        fi[0]=a.x; fi[1]=a.y; fi[2]=a.z; fi[3]=a.w;
        fi[4]=c2.x; fi[5]=c2.y; fi[6]=c2.z; fi[7]=c2.w;
        fi[8]=c3.x; fi[9]=c3.y; fi[10]=c3.z; fi[11]=c3.w;
        fi[12]=c4.x; fi[13]=c4.y; fi[14]=c4.z; fi[15]=c4.w;
    }
    float ci[3], rel[3];
    {
        const float* cp = coordsIn + (size_t)n * 3;
        const float* cq = coordsIn + ((size_t)b * SL + j) * 3;
        ci[0] = cp[0]; ci[1] = cp[1]; ci[2] = cp[2];
        rel[0] = ci[0] - cq[0]; rel[1] = ci[1] - cq[1]; rel[2] = ci[2] - cq[2];
    }
    const float rd = fmaf(rel[0], rel[0], fmaf(rel[1], rel[1], rel[2] * rel[2]));

    // partial prefetch of P before the barrier (independent of LDS)
    const int ub = h * 36;
    const float* PiP = Pbuf + (size_t)n * PST + ub;
    const float* PjP = Pbuf + ((size_t)b * SL + j) * PST + 72 + ub;
    float4 pa = *(const float4*)PiP;
    float4 pb = *(const float4*)PjP;

    __syncthreads();   // weights staged

    // ---- edge MLP layer-1 via precomputed partials; layer-2 accumulate ----
    float macc[16];
#pragma unroll
    for (int v = 0; v < 16; ++v) macc[v] = h ? 0.0f : s_eb2[v];
#pragma unroll
    for (int c4 = 0; c4 < 9; ++c4) {
        float4 na, nb;
        if (c4 < 8) {
            na = *(const float4*)(PiP + 4 * (c4 + 1));
            nb = *(const float4*)(PjP + 4 * (c4 + 1));
        }
        const int u0 = ub + c4 * 4;
        const float hu0 = silu_f(fmaf(rd, s_w1r[u0 + 0], pa.x + pb.x));
        const float hu1 = silu_f(fmaf(rd, s_w1r[u0 + 1], pa.y + pb.y));
        const float hu2 = silu_f(fmaf(rd, s_w1r[u0 + 2], pa.z + pb.z));
        const float hu3 = silu_f(fmaf(rd, s_w1r[u0 + 3], pa.w + pb.w));
        const float* w2r = &s_w2e[u0 * 16];
#pragma unroll
        for (int v = 0; v < 16; ++v) {
            float m0 = fmaf(hu0, w2r[v], macc[v]);
            float m1 = fmaf(hu1, w2r[16 + v], m0);
            float m2 = fmaf(hu2, w2r[32 + v], m1);
            macc[v] = fmaf(hu3, w2r[48 + v], m2);
        }
        if (c4 < 8) { pa = na; pb = nb; }
    }

    // ---- combine halves via LDS (stride-20, 16B-aligned) ----
    float4* exq = (float4*)&s_ex[((p << 6) + lane) * 20];
    if (h) {
        exq[0] = make_float4(macc[0], macc[1], macc[2], macc[3]);
        exq[1] = make_float4(macc[4], macc[5], macc[6], macc[7]);
        exq[2] = make_float4(macc[8], macc[9], macc[10], macc[11]);
        exq[3] = make_float4(macc[12], macc[13], macc[14], macc[15]);
    }
    __syncthreads();
    float mm[16];
    if (!h) {
        float4 e0 = exq[0], e1 = exq[1], e2 = exq[2], e3 = exq[3];
        macc[0]+=e0.x; macc[1]+=e0.y; macc[2]+=e0.z; macc[3]+=e0.w;
        macc[4]+=e1.x; macc[5]+=e1.y; macc[6]+=e1.z; macc[7]+=e1.w;
        macc[8]+=e2.x; macc[9]+=e2.y; macc[10]+=e2.z; macc[11]+=e2.w;
        macc[12]+=e3.x; macc[13]+=e3.y; macc[14]+=e3.z; macc[15]+=e3.w;
#pragma unroll
        for (int v = 0; v < 16; ++v) mm[v] = silu_f(macc[v]);
        exq[0] = make_float4(mm[0], mm[1], mm[2], mm[3]);
        exq[1] = make_float4(mm[4], mm[5], mm[6], mm[7]);
        exq[2] = make_float4(mm[8], mm[9], mm[10], mm[11]);
        exq[3] = make_float4(mm[12], mm[13], mm[14], mm[15]);
    }
    __syncthreads();
    if (h) {
        float4 e0 = exq[0], e1 = exq[1], e2 = exq[2], e3 = exq[3];
        mm[0]=e0.x; mm[1]=e0.y; mm[2]=e0.z; mm[3]=e0.w;
        mm[4]=e1.x; mm[5]=e1.y; mm[6]=e1.z; mm[7]=e1.w;
        mm[8]=e2.x; mm[9]=e2.y; mm[10]=e2.z; mm[11]=e2.w;
        mm[12]=e3.x; mm[13]=e3.y; mm[14]=e3.z; mm[15]=e3.w;
    }

    // ---- coors MLP, t-range [h*32, h*32+32) ----
    const int tb = h * 32;
    float wa = 0.f;
#pragma unroll 4
    for (int tt = 0; tt < 32; ++tt) {
        const float* cr = &s_cw1[(tb + tt) * 16];
        float a0 = s_cb1[tb + tt], a1 = 0.f;
#pragma unroll
        for (int v = 0; v < 16; v += 2) {
            a0 = fmaf(mm[v], cr[v], a0);
            a1 = fmaf(mm[v + 1], cr[v + 1], a1);
        }
        wa = fmaf(silu_f(a0 + a1), s_cw2v[tb + tt], wa);
    }
    s_ex[((p << 6) + lane) * 20 + 16 + h] = wa;
    __syncthreads();
    const float wao = s_ex[((p << 6) + lane) * 20 + 17 - h];
    const float we = em ? (wa + wao + s_cb2v) : 0.f;

    // ---- coordinate update: reduce over 8 edges of node ----
    float wr0 = we * rel[0], wr1 = we * rel[1], wr2 = we * rel[2];
#pragma unroll
    for (int s = 1; s < 8; s <<= 1) {
        wr0 += __shfl_xor(wr0, s, 64);
        wr1 += __shfl_xor(wr1, s, 64);
        wr2 += __shfl_xor(wr2, s, 64);
    }
    if (!h && k == 0) {
        coordsOut[(size_t)n * 3 + 0] = ci[0] + wr0;
        coordsOut[(size_t)n * 3 + 1] = ci[1] + wr1;
        coordsOut[(size_t)n * 3 + 2] = ci[2] + wr2;
    }

    // ---- m_i ----
    float mi_[16];
#pragma unroll
    for (int v = 0; v < 16; ++v) mi_[v] = em ? mm[v] : 0.f;
#pragma unroll
    for (int s = 1; s < 8; s <<= 1) {
#pragma unroll
        for (int v = 0; v < 16; ++v) mi_[v] += __shfl_xor(mi_[v], s, 64);
    }

    // ---- LayerNorm ----
    float mu = 0.f;
#pragma unroll
    for (int c = 0; c < 16; ++c) mu += fi[c];
    mu *= 0.0625f;
    float var = 0.f;
#pragma unroll
    for (int c = 0; c < 16; ++c) { const float dd = fi[c] - mu; var = fmaf(dd, dd, var); }
    var *= 0.0625f;
    const float rs = rsqrtf(var + LN_EPS);
    float nn[16];
#pragma unroll
    for (int c = 0; c < 16; ++c) nn[c] = fmaf((fi[c] - mu) * rs, s_lng[c], s_lnb[c]);

    // ---- node MLP hidden: lane k owns units k*4..k*4+3 (fully deduped) ----
    float nh[4];
#pragma unroll
    for (int q = 0; q < 4; ++q) {
        const int u = k * 4 + q;
        const float* nr = &s_nw1[u * 36];
        float a0 = s_nb1[u], a1 = 0.f;
#pragma unroll
        for (int c = 0; c < 16; c += 2) {
            a0 = fmaf(nn[c], nr[c], a0);
            a1 = fmaf(nn[c + 1], nr[c + 1], a1);
        }
#pragma unroll
        for (int v = 0; v < 16; v += 2) {
            a0 = fmaf(mi_[v], nr[16 + v], a0);
            a1 = fmaf(mi_[v + 1], nr[16 + v + 1], a1);
        }
        nh[q] = silu_f(a0 + a1);
    }

    // ---- node MLP out: lane k computes channels 2k, 2k+1 via shfl gather ----
    const int c0 = 2 * k, c1 = 2 * k + 1;
    const float* w2a = &s_nw2[c0 * 36];
    const float* w2b = &s_nw2[c1 * 36];
    float o0 = s_nb2[c0], o1 = s_nb2[c1];
    const int lbase = lane & ~7;
#pragma unroll
    for (int u = 0; u < 32; ++u) {
        const float v = __shfl(nh[u & 3], lbase + (u >> 2), 64);
        o0 = fmaf(v, w2a[u], o0);
        o1 = fmaf(v, w2b[u], o1);
    }
    if (!h) {
        const float fo0 = fi[c0] + o0;
        const float fo1 = fi[c1] + o1;
        ((float2*)featsOut)[(size_t)n * 8 + k] = make_float2(fo0, fo1);
        const int nl = (p << 3) + (lane >> 3);
        s_nf[nl * 20 + c0] = fo0;
        s_nf[nl * 20 + c1] = fo1;
    }

    // ---- fused phi for layer d+1: P_out for this block's 16 nodes ----
    if (d < 2) {
        __syncthreads();
        const int nl2 = tid >> 4;
        const int sub = tid & 15;
        const int gnode = blockIdx.x * 16 + nl2;
        float fr[16];
        {
            const float4* fp = (const float4*)&s_nf[nl2 * 20];   // broadcast reads
            float4 q0 = fp[0], q1 = fp[1], q2 = fp[2], q3 = fp[3];
            fr[0]=q0.x; fr[1]=q0.y; fr[2]=q0.z; fr[3]=q0.w;
            fr[4]=q1.x; fr[5]=q1.y; fr[6]=q1.z; fr[7]=q1.w;
            fr[8]=q2.x; fr[9]=q2.y; fr[10]=q2.z; fr[11]=q2.w;
            fr[12]=q3.x; fr[13]=q3.y; fr[14]=q3.z; fr[15]=q3.w;
        }
        float* Pout = PbufOut + (size_t)gnode * PST;
#pragma unroll
        for (int q = 0; q < 9; ++q) {
            const int col = sub + (q << 4);
            const int ch = (col >= 108) ? 3 : (col >= 72) ? 2 : (col >= 36) ? 1 : 0;
            const int uu = col - ch * 36;
            const bool valid = uu < 33;
            const int u = ((ch & 1) ? 33 : 0) + uu;
            const int uc = valid ? u : 0;
            const int widx = valid ? ((ch < 2) ? u : 66 + u) : 0;
            float a0 = (valid && ch < 2) ? s_eb1n[uc] : 0.0f;
            float a1 = 0.f, a2 = 0.f, a3 = 0.f;
            const float* wr = &s_wphi[widx * 20];
#pragma unroll
            for (int cc = 0; cc < 16; cc += 4) {
                a0 = fmaf(fr[cc + 0], wr[cc + 0], a0);
                a1 = fmaf(fr[cc + 1], wr[cc + 1], a1);
                a2 = fmaf(fr[cc + 2], wr[cc + 2], a2);
                a3 = fmaf(fr[cc + 3], wr[cc + 3], a3);
            }
            Pout[col] = valid ? ((a0 + a1) + (a2 + a3)) : 0.0f;
        }
    }
}

// ---------------- final projection ----------------
__global__ __launch_bounds__(256) void final_kernel(
    const float* __restrict__ feats, const float* __restrict__ fw,
    const float* __restrict__ fb, float* __restrict__ out)
{
    const int nid = blockIdx.x * 256 + threadIdx.x;
    if (nid >= NB * SL) return;
    float f[DIM];
#pragma unroll
    for (int c = 0; c < DIM; ++c) f[c] = feats[nid * DIM + c];
#pragma unroll
    for (int o = 0; o < 3; ++o) {
        float acc = fb[o];
#pragma unroll
        for (int c = 0; c < DIM; ++c) acc = fmaf(f[c], fw[c * 3 + o], acc);
        out[nid * 3 + o] = acc;
    }
}

extern "C" void kernel_launch(void* const* d_in, const int* in_sizes, int n_in,
                              void* d_out, int out_size, void* d_ws, size_t ws_size,
                              hipStream_t stream) {
    const float* coords    = (const float*)d_in[0];
    const int*   residues  = (const int*)d_in[1];
    const int*   lengths   = (const int*)d_in[2];
    const float* token_emb = (const float*)d_in[3];
    const float* pos_emb   = (const float*)d_in[4];
    const float* ew1 = (const float*)d_in[5];
    const float* eb1 = (const float*)d_in[6];
    const float* ew2 = (const float*)d_in[7];
    const float* eb2 = (const float*)d_in[8];
    const float* cw1 = (const float*)d_in[9];
    const float* cb1 = (const float*)d_in[10];
    const float* cw2 = (const float*)d_in[11];
    const float* cb2 = (const float*)d_in[12];
    const float* lng = (const float*)d_in[13];
    const float* lnb = (const float*)d_in[14];
    const float* nw1 = (const float*)d_in[15];
    const float* nb1 = (const float*)d_in[16];
    const float* nw2 = (const float*)d_in[17];
    const float* nb2 = (const float*)d_in[18];
    const float* fw  = (const float*)d_in[19];
    const float* fb  = (const float*)d_in[20];

    float* ws = (float*)d_ws;
    float* coordsA = ws;
    float* coordsB = coordsA + NB * SL * 3;
    float* featsA  = coordsB + NB * SL * 3;
    float* featsB  = featsA + NB * SL * DIM;
    int*   idxbuf  = (int*)(featsB + NB * SL * DIM);
    float* w1tp = (float*)(idxbuf + NB * SL * KNN);     // 3*132*16
    float* w1rp = w1tp + 3 * 132 * 16;                  // 3*72
    float* w2p  = w1rp + 3 * 72;                        // 3*72*16
    float* cw1t = w2p + 3 * 72 * 16;                    // 3*64*16
    float* nw1t = cw1t + 3 * CH * 16;                   // 3*32*32
    float* nw2t = nw1t + 3 * NHID * 32;                 // 3*16*32
    float* PbufA = nw2t + 3 * 16 * 32;                  // 16384*144
    float* PbufB = PbufA + (size_t)NB * SL * PST;       // 16384*144

    pack_kernel<<<32, 256, 0, stream>>>(ew1, ew2, cw1, nw1, nw2, w1tp, w1rp, w2p, cw1t, nw1t, nw2t);
    init_kernel<<<NB * SL * 4 / 256, 256, 0, stream>>>(coords, residues, token_emb, pos_emb,
                                                        w1tp, eb1, coordsA, featsA, PbufA);

    float* cIn = coordsA; float* cOut = coordsB;
    float* fIn = featsA;  float* fOut = featsB;
    float* pIn = PbufA;   float* pOut = PbufB;
    for (int d = 0; d < 3; ++d) {
        knn_kernel<<<NB * SL / 64, 1024, 0, stream>>>(cIn, lengths, idxbuf);
        layer_kernel<<<NB * SL * KNN / 128, 256, 0, stream>>>(d, cIn, cOut, fIn, fOut, pIn, idxbuf, lengths,
            w1rp, w2p, eb2, cw1t, cb1, cw2, cb2, lng, lnb, nw1t, nb1, nw2t, nb2,
            w1tp, eb1, pOut);
        float* t;
        t = cIn; cIn = cOut; cOut = t;
        t = fIn; fIn = fOut; fOut = t;
        t = pIn; pIn = pOut; pOut = t;
    }

    final_kernel<<<NB * SL / 256, 256, 0, stream>>>(fIn, fw, fb, (float*)d_out);
}

// Round 3
// 280.329 us; speedup vs baseline: 1.1459x; 1.0460x over previous
//
#include <hip/hip_runtime.h>
#include <math.h>

typedef unsigned long long u64;
typedef unsigned int u32;

#define NB 16
#define SL 1024
#define DIM 16
#define MDIM 16
#define KNN 8
#define CH 64    /* coors hidden */
#define NHID 32  /* node hidden */
#define LN_EPS 1e-5f
#define PST 144  /* P row stride: 4 chunks of 36 (33 units + 3 zero pad) */

// silu via hw exp + hw rcp: 5 VALU vs ~12 for div-based (no -ffast-math here)
__device__ __forceinline__ float silu_f(float x) {
    const float e = __expf(-x);
    return x * __builtin_amdgcn_rcpf(1.0f + e);
}

// ---------------- init: feats/coords copy + fused phi for layer 0 ----------------
// 4 threads per node; thread part p computes P chunk p (36 cols).
__global__ __launch_bounds__(256) void init_kernel(
    const float* __restrict__ coords, const int* __restrict__ residues,
    const float* __restrict__ token_emb, const float* __restrict__ pos_emb,
    const float* __restrict__ w1tp, const float* __restrict__ g_eb1,
    float* __restrict__ coordsA, float* __restrict__ featsA,
    float* __restrict__ Pout)
{
    const int t = blockIdx.x * 256 + threadIdx.x;
    const int node = t >> 2;
    const int part = t & 3;
    const int l = node & (SL - 1);
    const int r = residues[node];
    float f[16];
    {
        const float4* te = (const float4*)(token_emb + (size_t)r * DIM);
        const float4* pe = (const float4*)(pos_emb + (size_t)l * DIM);
#pragma unroll
        for (int q = 0; q < 4; ++q) {
            float4 a = te[q], b4 = pe[q];
            f[4*q+0] = a.x + b4.x; f[4*q+1] = a.y + b4.y;
            f[4*q+2] = a.z + b4.z; f[4*q+3] = a.w + b4.w;
        }
    }
    if (part == 0) {
        float4* fo = (float4*)(featsA + (size_t)node * DIM);
#pragma unroll
        for (int q = 0; q < 4; ++q)
            fo[q] = make_float4(f[4*q], f[4*q+1], f[4*q+2], f[4*q+3]);
        coordsA[node * 3 + 0] = coords[node * 3 + 0];
        coordsA[node * 3 + 1] = coords[node * 3 + 1];
        coordsA[node * 3 + 2] = coords[node * 3 + 2];
    }
    const int ubase = (part & 1) * 33;
    const int wbase = (part < 2) ? 0 : 66;
    float res[36];
    res[33] = 0.f; res[34] = 0.f; res[35] = 0.f;
#pragma unroll
    for (int oo = 0; oo < 33; ++oo) {     // FULL unroll: res[] stays in registers
        const int u = ubase + oo;
        const float* wr = w1tp + (wbase + u) * 16;
        float a0 = (part < 2) ? g_eb1[u] : 0.0f;
        float a1 = 0.f, a2 = 0.f, a3 = 0.f;
#pragma unroll
        for (int c = 0; c < 16; c += 4) {
            a0 = fmaf(f[c + 0], wr[c + 0], a0);
            a1 = fmaf(f[c + 1], wr[c + 1], a1);
            a2 = fmaf(f[c + 2], wr[c + 2], a2);
            a3 = fmaf(f[c + 3], wr[c + 3], a3);
        }
        res[oo] = (a0 + a1) + (a2 + a3);
    }
    float4* op = (float4*)(Pout + (size_t)node * PST + part * 36);
#pragma unroll
    for (int q = 0; q < 9; ++q)
        op[q] = make_float4(res[4*q], res[4*q+1], res[4*q+2], res[4*q+3]);
}

// ---------------- weight transpose/pack ----------------
__global__ __launch_bounds__(256) void pack_kernel(
    const float* __restrict__ ew1, const float* __restrict__ ew2,
    const float* __restrict__ cw1,
    const float* __restrict__ nw1, const float* __restrict__ nw2,
    float* __restrict__ w1tp, float* __restrict__ w1rp, float* __restrict__ w2p,
    float* __restrict__ cw1t, float* __restrict__ nw1t, float* __restrict__ nw2t)
{
    const int stride = gridDim.x * 256;
    const int t0 = blockIdx.x * 256 + threadIdx.x;
    // w1tp[d][132][16]: o<66 -> Pi cols (input c),  o>=66 -> Pj cols (input 16+c)
    for (int idx = t0; idx < 3 * 132 * 16; idx += stride) {
        int d = idx / (132 * 16); int r = idx - d * 132 * 16; int o = r >> 4; int c = r & 15;
        int u = (o < 66) ? o : (o - 66);
        int cc = (o < 66) ? c : (16 + c);
        w1tp[idx] = ew1[(d * 33 + cc) * 66 + u];
    }
    // w1rp[d][72]: rd-row, split into 2 padded halves of 36 (rows 33..35 zero)
    for (int idx = t0; idx < 3 * 72; idx += stride) {
        int d = idx / 72; int o = idx - d * 72; int hh = o / 36; int uu = o - hh * 36;
        w1rp[idx] = (uu < 33) ? ew1[(d * 33 + 32) * 66 + hh * 33 + uu] : 0.0f;
    }
    // w2p[d][72][16]: edge w2 rows, padded halves (pad rows zero)
    for (int idx = t0; idx < 3 * 72 * 16; idx += stride) {
        int d = idx / (72 * 16); int r = idx - d * 72 * 16; int u = r >> 4; int v = r & 15;
        int hh = u / 36; int uu = u - hh * 36;
        w2p[idx] = (uu < 33) ? ew2[(d * 66 + hh * 33 + uu) * 16 + v] : 0.0f;
    }
    for (int idx = t0; idx < 3 * CH * 16; idx += stride) {
        int d = idx / (CH * 16); int r = idx - d * CH * 16; int t = r >> 4; int v = r & 15;
        cw1t[(d * CH + t) * 16 + v] = cw1[(d * 16 + v) * CH + t];
    }
    for (int idx = t0; idx < 3 * NHID * 32; idx += stride) {
        int d = idx / (NHID * 32); int r = idx - d * NHID * 32; int u = r >> 5; int c = r & 31;
        nw1t[(d * NHID + u) * 32 + c] = nw1[(d * 32 + c) * NHID + u];
    }
    for (int idx = t0; idx < 3 * 16 * 32; idx += stride) {
        int d = idx / (16 * 32); int r = idx - d * 16 * 32; int c = r >> 5; int u = r & 31;
        nw2t[(d * 16 + c) * 32 + u] = nw2[(d * 32 + u) * 16 + c];
    }
}

// ---------------- kNN: float4-staged candidates, min/max insertion ladder ----------------
__device__ __forceinline__ void merge8(u32* a, const u32* bb) {
    u32 c[8];
#pragma unroll
    for (int t = 0; t < 8; ++t) c[t] = min(a[t], bb[7 - t]);
#define MCAS(x, y) { u32 mn = min(c[x], c[y]); u32 mx = max(c[x], c[y]); c[x] = mn; c[y] = mx; }
    MCAS(0, 4) MCAS(1, 5) MCAS(2, 6) MCAS(3, 7)
    MCAS(0, 2) MCAS(1, 3) MCAS(4, 6) MCAS(5, 7)
    MCAS(0, 1) MCAS(2, 3) MCAS(4, 5) MCAS(6, 7)
#undef MCAS
#pragma unroll
    for (int t = 0; t < 8; ++t) a[t] = c[t];
}

__global__ __launch_bounds__(1024) void knn_kernel(
    const float* __restrict__ coords, const int* __restrict__ lengths,
    int* __restrict__ idxbuf)
{
    __shared__ __align__(16) float4 s_cand[SL];   // 16 KB (padded xyz)
    __shared__ u32 lists[16][64][9];              // 36 KB, pad 9 vs bank conflicts
    const int tid = threadIdx.x;
    const int b = blockIdx.x >> 4;
    const int i0 = (blockIdx.x & 15) << 6;
    const int len = lengths[b];
    const float* cb = coords + (size_t)b * SL * 3;
    for (int idx = tid; idx < SL; idx += 1024) {
        const float* cp = cb + idx * 3;
        s_cand[idx] = make_float4(cp[0], cp[1], cp[2], 0.0f);
    }
    __syncthreads();

    const int wv = tid >> 6;     // candidate slice 0..15
    const int lane = tid & 63;   // query within group
    const int i = i0 + lane;
    const bool mi = i < len;
    const float4 qi = s_cand[i];
    const float xi = qi.x, yi = qi.y, zi = qi.z;

    u32 lst[8];
#pragma unroll
    for (int t = 0; t < 8; ++t) lst[t] = 0xFFFFFFFFu;

    const int jbase = wv << 6;
#pragma unroll 4
    for (int jj = 0; jj < 64; ++jj) {
        const int j = jbase + jj;
        const float4 cj = s_cand[j];   // wave-uniform addr -> LDS broadcast
        const float dx = xi - cj.x, dy = yi - cj.y, dz = zi - cj.z;
        const float dist = dx * dx + dy * dy + dz * dz;
        const int dij = j - i;
        const bool pm = mi && (j < len);           // (j<len) is wave-uniform scalar
        const bool adjx = (dij == 1) | (dij == -1);
        float v = pm ? (adjx ? 0.0f : dist) : 1e5f;
        v = (dij == 0) ? -1.0f : v;
        u32 bits = __float_as_uint(v);
        bits ^= (u32)((int)bits >> 31) | 0x80000000u;
        const u32 key = (bits & 0xFFFFFC00u) | (u32)j;
        // sorted-insert: lst[p] = min(max(key, lst[p-1]), lst[p]) -- 2 VALU/level
#pragma unroll
        for (int p = 7; p >= 1; --p)
            lst[p] = min(max(key, lst[p - 1]), lst[p]);
        lst[0] = min(key, lst[0]);
    }

#pragma unroll
    for (int t = 0; t < 8; ++t) lists[wv][lane][t] = lst[t];
    __syncthreads();

    if (tid < 512) {
        const int p = tid >> 6, q = tid & 63;
        u32 a[8], bb[8];
#pragma unroll
        for (int t = 0; t < 8; ++t) { a[t] = lists[2 * p][q][t]; bb[t] = lists[2 * p + 1][q][t]; }
        merge8(a, bb);
#pragma unroll
        for (int t = 0; t < 8; ++t) lists[2 * p][q][t] = a[t];
    }
    __syncthreads();
    if (tid < 256) {
        const int p = tid >> 6, q = tid & 63;
        u32 a[8], bb[8];
#pragma unroll
        for (int t = 0; t < 8; ++t) { a[t] = lists[4 * p][q][t]; bb[t] = lists[4 * p + 2][q][t]; }
        merge8(a, bb);
#pragma unroll
        for (int t = 0; t < 8; ++t) lists[4 * p][q][t] = a[t];
    }
    __syncthreads();
    if (tid < 128) {
        const int p = tid >> 6, q = tid & 63;
        u32 a[8], bb[8];
#pragma unroll
        for (int t = 0; t < 8; ++t) { a[t] = lists[8 * p][q][t]; bb[t] = lists[8 * p + 4][q][t]; }
        merge8(a, bb);
#pragma unroll
        for (int t = 0; t < 8; ++t) lists[8 * p][q][t] = a[t];
    }
    __syncthreads();
    if (tid < 64) {
        const int q = tid;
        u32 a[8], bb[8];
#pragma unroll
        for (int t = 0; t < 8; ++t) { a[t] = lists[0][q][t]; bb[t] = lists[8][q][t]; }
        merge8(a, bb);
        const size_t node = (size_t)b * SL + i0 + q;
        int4 r0 = make_int4((int)(a[0] & 1023u), (int)(a[1] & 1023u), (int)(a[2] & 1023u), (int)(a[3] & 1023u));
        int4 r1 = make_int4((int)(a[4] & 1023u), (int)(a[5] & 1023u), (int)(a[6] & 1023u), (int)(a[7] & 1023u));
        ((int4*)idxbuf)[node * 2 + 0] = r0;
        ((int4*)idxbuf)[node * 2 + 1] = r1;
    }
}

// ---------------- EGNN layer: factored edge MLP + fused next-layer phi epilogue ----------------
__global__ __launch_bounds__(256, 5) void layer_kernel(
    const int d,
    const float* __restrict__ coordsIn, float* __restrict__ coordsOut,
    const float* __restrict__ featsIn, float* __restrict__ featsOut,
    const float* __restrict__ Pbuf,
    const int* __restrict__ idxbuf, const int* __restrict__ lengths,
    const float* __restrict__ w1rp, const float* __restrict__ w2p,
    const float* __restrict__ g_eb2,
    const float* __restrict__ cw1t, const float* __restrict__ g_cb1,
    const float* __restrict__ g_cw2, const float* __restrict__ g_cb2,
    const float* __restrict__ g_lng, const float* __restrict__ g_lnb,
    const float* __restrict__ nw1t, const float* __restrict__ g_nb1,
    const float* __restrict__ nw2t, const float* __restrict__ g_nb2,
    const float* __restrict__ w1tp_all, const float* __restrict__ g_eb1,
    float* __restrict__ PbufOut)
{
    __shared__ float s_w2e[72 * 16];                 // 4608 B
    __shared__ float s_w1r[72];
    __shared__ float s_cw1[CH * 16];                 // 4096 B
    __shared__ float s_cw2v[CH];
    __shared__ float s_nw1[NHID * 36];               // padded rows: bank spread
    __shared__ float s_nw2[16 * 36];
    __shared__ float s_eb2[16], s_cb1[CH];
    __shared__ float s_lng[16], s_lnb[16], s_nb1[32], s_nb2[16];
    __shared__ float s_cb2v;
    __shared__ __align__(16) float s_ex[2 * 64 * 20];   // wave-pair exchange, 10240 B
    __shared__ __align__(16) float s_nf[16 * 20];       // new feats rows, 1280 B

    const int tid = threadIdx.x;
    for (int t = tid; t < 72 * 16; t += 256) s_w2e[t] = w2p[d * 72 * 16 + t];
    for (int t = tid; t < CH * 16; t += 256) s_cw1[t] = cw1t[d * CH * 16 + t];
    for (int t = tid; t < NHID * 32; t += 256) s_nw1[(t >> 5) * 36 + (t & 31)] = nw1t[d * NHID * 32 + t];
    for (int t = tid; t < 16 * 32; t += 256) s_nw2[(t >> 5) * 36 + (t & 31)] = nw2t[d * 16 * 32 + t];
    if (tid < 72) s_w1r[tid] = w1rp[d * 72 + tid];
    if (tid < CH) { s_cw2v[tid] = g_cw2[d * CH + tid]; s_cb1[tid] = g_cb1[d * CH + tid]; }
    if (tid < 16) {
        s_eb2[tid] = g_eb2[d * 16 + tid];
        s_lng[tid] = g_lng[d * 16 + tid];
        s_lnb[tid] = g_lnb[d * 16 + tid];
        s_nb2[tid] = g_nb2[d * 16 + tid];
    }
    if (tid < 32) s_nb1[tid] = g_nb1[d * 32 + tid];
    if (tid == 0) s_cb2v = g_cb2[d];

    const int wvid = tid >> 6;
    const int h = wvid & 1;          // wave-uniform half
    const int p = wvid >> 1;         // wave pair
    const int lane = tid & 63;
    const int e = blockIdx.x * 128 + p * 64 + lane;
    const int n = e >> 3;
    const int b = n >> 10;
    const int i = n & (SL - 1);
    const int k = lane & 7;
    const int len = lengths[b];
    const int j = idxbuf[e];
    const bool em = (i < len) && (j < len);

    // ---- inputs ----
    float fi[16];
    {
        const float4* pp = (const float4*)(featsIn + (size_t)n * DIM);
        float4 a = pp[0], c2 = pp[1], c3 = pp[2], c4 = pp[3];
        fi[0]=a.x; fi[1]=a.y; fi[2]=a.z; fi[3]=a.w;
        fi[4]=c2.x; fi[5]=c2.y; fi[6]=c2.z; fi[7]=c2.w;
        fi[8]=c3.x; fi[9]=c3.y; fi[10]=c3.z; fi[11]=c3.w;
        fi[12]=c4.x; fi[13]=c4.y; fi[14]=c4.z; fi[15]=c4.w;
    }
    float ci[3], rel[3];
    {
        const float* cp = coordsIn + (size_t)n * 3;
        const float* cq = coordsIn + ((size_t)b * SL + j) * 3;
        ci[0] = cp[0]; ci[1] = cp[1]; ci[2] = cp[2];
        rel[0] = ci[0] - cq[0]; rel[1] = ci[1] - cq[1]; rel[2] = ci[2] - cq[2];
    }
    const float rd = fmaf(rel[0], rel[0], fmaf(rel[1], rel[1], rel[2] * rel[2]));

    // partial prefetch of P before the barrier (independent of LDS)
    const int ub = h * 36;
    const float* PiP = Pbuf + (size_t)n * PST + ub;
    const float* PjP = Pbuf + ((size_t)b * SL + j) * PST + 72 + ub;
    float4 pa = *(const float4*)PiP;
    float4 pb = *(const float4*)PjP;

    __syncthreads();   // weights staged

    // ---- edge MLP layer-1 via precomputed partials; layer-2 accumulate ----
    float macc[16];
#pragma unroll
    for (int v = 0; v < 16; ++v) macc[v] = h ? 0.0f : s_eb2[v];
#pragma unroll
    for (int c4 = 0; c4 < 9; ++c4) {
        float4 na, nb;
        if (c4 < 8) {
            na = *(const float4*)(PiP + 4 * (c4 + 1));
            nb = *(const float4*)(PjP + 4 * (c4 + 1));
        }
        const int u0 = ub + c4 * 4;
        const float hu0 = silu_f(fmaf(rd, s_w1r[u0 + 0], pa.x + pb.x));
        const float hu1 = silu_f(fmaf(rd, s_w1r[u0 + 1], pa.y + pb.y));
        const float hu2 = silu_f(fmaf(rd, s_w1r[u0 + 2], pa.z + pb.z));
        const float hu3 = silu_f(fmaf(rd, s_w1r[u0 + 3], pa.w + pb.w));
        const float* w2r = &s_w2e[u0 * 16];
#pragma unroll
        for (int v = 0; v < 16; ++v) {
            float m0 = fmaf(hu0, w2r[v], macc[v]);
            float m1 = fmaf(hu1, w2r[16 + v], m0);
            float m2 = fmaf(hu2, w2r[32 + v], m1);
            macc[v] = fmaf(hu3, w2r[48 + v], m2);
        }
        if (c4 < 8) { pa = na; pb = nb; }
    }

    // ---- combine halves via LDS (stride-20, 16B-aligned) ----
    float4* exq = (float4*)&s_ex[((p << 6) + lane) * 20];
    if (h) {
        exq[0] = make_float4(macc[0], macc[1], macc[2], macc[3]);
        exq[1] = make_float4(macc[4], macc[5], macc[6], macc[7]);
        exq[2] = make_float4(macc[8], macc[9], macc[10], macc[11]);
        exq[3] = make_float4(macc[12], macc[13], macc[14], macc[15]);
    }
    __syncthreads();
    float mm[16];
    if (!h) {
        float4 e0 = exq[0], e1 = exq[1], e2 = exq[2], e3 = exq[3];
        macc[0]+=e0.x; macc[1]+=e0.y; macc[2]+=e0.z; macc[3]+=e0.w;
        macc[4]+=e1.x; macc[5]+=e1.y; macc[6]+=e1.z; macc[7]+=e1.w;
        macc[8]+=e2.x; macc[9]+=e2.y; macc[10]+=e2.z; macc[11]+=e2.w;
        macc[12]+=e3.x; macc[13]+=e3.y; macc[14]+=e3.z; macc[15]+=e3.w;
#pragma unroll
        for (int v = 0; v < 16; ++v) mm[v] = silu_f(macc[v]);
        exq[0] = make_float4(mm[0], mm[1], mm[2], mm[3]);
        exq[1] = make_float4(mm[4], mm[5], mm[6], mm[7]);
        exq[2] = make_float4(mm[8], mm[9], mm[10], mm[11]);
        exq[3] = make_float4(mm[12], mm[13], mm[14], mm[15]);
    }
    __syncthreads();
    if (h) {
        float4 e0 = exq[0], e1 = exq[1], e2 = exq[2], e3 = exq[3];
        mm[0]=e0.x; mm[1]=e0.y; mm[2]=e0.z; mm[3]=e0.w;
        mm[4]=e1.x; mm[5]=e1.y; mm[6]=e1.z; mm[7]=e1.w;
        mm[8]=e2.x; mm[9]=e2.y; mm[10]=e2.z; mm[11]=e2.w;
        mm[12]=e3.x; mm[13]=e3.y; mm[14]=e3.z; mm[15]=e3.w;
    }

    // ---- coors MLP, t-range [h*32, h*32+32) ----
    const int tb = h * 32;
    float wa = 0.f;
#pragma unroll 4
    for (int tt = 0; tt < 32; ++tt) {
        const float* cr = &s_cw1[(tb + tt) * 16];
        float a0 = s_cb1[tb + tt], a1 = 0.f;
#pragma unroll
        for (int v = 0; v < 16; v += 2) {
            a0 = fmaf(mm[v], cr[v], a0);
            a1 = fmaf(mm[v + 1], cr[v + 1], a1);
        }
        wa = fmaf(silu_f(a0 + a1), s_cw2v[tb + tt], wa);
    }
    s_ex[((p << 6) + lane) * 20 + 16 + h] = wa;
    __syncthreads();
    const float wao = s_ex[((p << 6) + lane) * 20 + 17 - h];
    const float we = em ? (wa + wao + s_cb2v) : 0.f;

    // ---- coordinate update: reduce over 8 edges of node ----
    float wr0 = we * rel[0], wr1 = we * rel[1], wr2 = we * rel[2];
#pragma unroll
    for (int s = 1; s < 8; s <<= 1) {
        wr0 += __shfl_xor(wr0, s, 64);
        wr1 += __shfl_xor(wr1, s, 64);
        wr2 += __shfl_xor(wr2, s, 64);
    }
    if (!h && k == 0) {
        coordsOut[(size_t)n * 3 + 0] = ci[0] + wr0;
        coordsOut[(size_t)n * 3 + 1] = ci[1] + wr1;
        coordsOut[(size_t)n * 3 + 2] = ci[2] + wr2;
    }

    // ---- m_i ----
    float mi_[16];
#pragma unroll
    for (int v = 0; v < 16; ++v) mi_[v] = em ? mm[v] : 0.f;
#pragma unroll
    for (int s = 1; s < 8; s <<= 1) {
#pragma unroll
        for (int v = 0; v < 16; ++v) mi_[v] += __shfl_xor(mi_[v], s, 64);
    }

    // ---- LayerNorm ----
    float mu = 0.f;
#pragma unroll
    for (int c = 0; c < 16; ++c) mu += fi[c];
    mu *= 0.0625f;
    float var = 0.f;
#pragma unroll
    for (int c = 0; c < 16; ++c) { const float dd = fi[c] - mu; var = fmaf(dd, dd, var); }
    var *= 0.0625f;
    const float rs = rsqrtf(var + LN_EPS);
    float nn[16];
#pragma unroll
    for (int c = 0; c < 16; ++c) nn[c] = fmaf((fi[c] - mu) * rs, s_lng[c], s_lnb[c]);

    // ---- node MLP hidden: lane k owns units k*4..k*4+3 (fully deduped) ----
    float nh[4];
#pragma unroll
    for (int q = 0; q < 4; ++q) {
        const int u = k * 4 + q;
        const float* nr = &s_nw1[u * 36];
        float a0 = s_nb1[u], a1 = 0.f;
#pragma unroll
        for (int c = 0; c < 16; c += 2) {
            a0 = fmaf(nn[c], nr[c], a0);
            a1 = fmaf(nn[c + 1], nr[c + 1], a1);
        }
#pragma unroll
        for (int v = 0; v < 16; v += 2) {
            a0 = fmaf(mi_[v], nr[16 + v], a0);
            a1 = fmaf(mi_[v + 1], nr[16 + v + 1], a1);
        }
        nh[q] = silu_f(a0 + a1);
    }

    // ---- node MLP out: lane k computes channels 2k, 2k+1 via shfl gather ----
    const int c0 = 2 * k, c1 = 2 * k + 1;
    const float* w2a = &s_nw2[c0 * 36];
    const float* w2b = &s_nw2[c1 * 36];
    float o0 = s_nb2[c0], o1 = s_nb2[c1];
    const int lbase = lane & ~7;
#pragma unroll
    for (int u = 0; u < 32; ++u) {
        const float v = __shfl(nh[u & 3], lbase + (u >> 2), 64);
        o0 = fmaf(v, w2a[u], o0);
        o1 = fmaf(v, w2b[u], o1);
    }
    if (!h) {
        const float fo0 = fi[c0] + o0;
        const float fo1 = fi[c1] + o1;
        ((float2*)featsOut)[(size_t)n * 8 + k] = make_float2(fo0, fo1);
        const int nl = (p << 3) + (lane >> 3);
        s_nf[nl * 20 + c0] = fo0;
        s_nf[nl * 20 + c1] = fo1;
    }

    // ---- fused phi for layer d+1: P_out for this block's 16 nodes ----
    // weights read straight from global (8.4 KB, identical across blocks -> L1/L2 resident)
    if (d < 2) {
        __syncthreads();
        const int nl2 = tid >> 4;
        const int sub = tid & 15;
        const int gnode = blockIdx.x * 16 + nl2;
        float fr[16];
        {
            const float4* fp = (const float4*)&s_nf[nl2 * 20];   // broadcast reads
            float4 q0 = fp[0], q1 = fp[1], q2 = fp[2], q3 = fp[3];
            fr[0]=q0.x; fr[1]=q0.y; fr[2]=q0.z; fr[3]=q0.w;
            fr[4]=q1.x; fr[5]=q1.y; fr[6]=q1.z; fr[7]=q1.w;
            fr[8]=q2.x; fr[9]=q2.y; fr[10]=q2.z; fr[11]=q2.w;
            fr[12]=q3.x; fr[13]=q3.y; fr[14]=q3.z; fr[15]=q3.w;
        }
        const float* wbase = w1tp_all + (d + 1) * 132 * 16;
        const float* bbase = g_eb1 + (d + 1) * 66;
        float* Pout = PbufOut + (size_t)gnode * PST;
#pragma unroll
        for (int q = 0; q < 9; ++q) {
            const int col = sub + (q << 4);
            const int ch = (col >= 108) ? 3 : (col >= 72) ? 2 : (col >= 36) ? 1 : 0;
            const int uu = col - ch * 36;
            const bool valid = uu < 33;
            const int u = ((ch & 1) ? 33 : 0) + uu;
            const int uc = valid ? u : 0;
            const int widx = valid ? ((ch < 2) ? u : 66 + u) : 0;
            float a0 = (valid && ch < 2) ? bbase[uc] : 0.0f;
            float a1 = 0.f, a2 = 0.f, a3 = 0.f;
            const float* wr = wbase + widx * 16;
#pragma unroll
            for (int cc = 0; cc < 16; cc += 4) {
                a0 = fmaf(fr[cc + 0], wr[cc + 0], a0);
                a1 = fmaf(fr[cc + 1], wr[cc + 1], a1);
                a2 = fmaf(fr[cc + 2], wr[cc + 2], a2);
                a3 = fmaf(fr[cc + 3], wr[cc + 3], a3);
            }
            Pout[col] = valid ? ((a0 + a1) + (a2 + a3)) : 0.0f;
        }
    }
}

// ---------------- final projection ----------------
__global__ __launch_bounds__(256) void final_kernel(
    const float* __restrict__ feats, const float* __restrict__ fw,
    const float* __restrict__ fb, float* __restrict__ out)
{
    const int nid = blockIdx.x * 256 + threadIdx.x;
    if (nid >= NB * SL) return;
    float f[DIM];
#pragma unroll
    for (int c = 0; c < DIM; ++c) f[c] = feats[nid * DIM + c];
#pragma unroll
    for (int o = 0; o < 3; ++o) {
        float acc = fb[o];
#pragma unroll
        for (int c = 0; c < DIM; ++c) acc = fmaf(f[c], fw[c * 3 + o], acc);
        out[nid * 3 + o] = acc;
    }
}

extern "C" void kernel_launch(void* const* d_in, const int* in_sizes, int n_in,
                              void* d_out, int out_size, void* d_ws, size_t ws_size,
                              hipStream_t stream) {
    const float* coords    = (const float*)d_in[0];
    const int*   residues  = (const int*)d_in[1];
    const int*   lengths   = (const int*)d_in[2];
    const float* token_emb = (const float*)d_in[3];
    const float* pos_emb   = (const float*)d_in[4];
    const float* ew1 = (const float*)d_in[5];
    const float* eb1 = (const float*)d_in[6];
    const float* ew2 = (const float*)d_in[7];
    const float* eb2 = (const float*)d_in[8];
    const float* cw1 = (const float*)d_in[9];
    const float* cb1 = (const float*)d_in[10];
    const float* cw2 = (const float*)d_in[11];
    const float* cb2 = (const float*)d_in[12];
    const float* lng = (const float*)d_in[13];
    const float* lnb = (const float*)d_in[14];
    const float* nw1 = (const float*)d_in[15];
    const float* nb1 = (const float*)d_in[16];
    const float* nw2 = (const float*)d_in[17];
    const float* nb2 = (const float*)d_in[18];
    const float* fw  = (const float*)d_in[19];
    const float* fb  = (const float*)d_in[20];

    float* ws = (float*)d_ws;
    float* coordsA = ws;
    float* coordsB = coordsA + NB * SL * 3;
    float* featsA  = coordsB + NB * SL * 3;
    float* featsB  = featsA + NB * SL * DIM;
    int*   idxbuf  = (int*)(featsB + NB * SL * DIM);
    float* w1tp = (float*)(idxbuf + NB * SL * KNN);     // 3*132*16
    float* w1rp = w1tp + 3 * 132 * 16;                  // 3*72
    float* w2p  = w1rp + 3 * 72;                        // 3*72*16
    float* cw1t = w2p + 3 * 72 * 16;                    // 3*64*16
    float* nw1t = cw1t + 3 * CH * 16;                   // 3*32*32
    float* nw2t = nw1t + 3 * NHID * 32;                 // 3*16*32
    float* PbufA = nw2t + 3 * 16 * 32;                  // 16384*144
    float* PbufB = PbufA + (size_t)NB * SL * PST;       // 16384*144

    pack_kernel<<<32, 256, 0, stream>>>(ew1, ew2, cw1, nw1, nw2, w1tp, w1rp, w2p, cw1t, nw1t, nw2t);
    init_kernel<<<NB * SL * 4 / 256, 256, 0, stream>>>(coords, residues, token_emb, pos_emb,
                                                        w1tp, eb1, coordsA, featsA, PbufA);

    float* cIn = coordsA; float* cOut = coordsB;
    float* fIn = featsA;  float* fOut = featsB;
    float* pIn = PbufA;   float* pOut = PbufB;
    for (int d = 0; d < 3; ++d) {
        knn_kernel<<<NB * SL / 64, 1024, 0, stream>>>(cIn, lengths, idxbuf);
        layer_kernel<<<NB * SL * KNN / 128, 256, 0, stream>>>(d, cIn, cOut, fIn, fOut, pIn, idxbuf, lengths,
            w1rp, w2p, eb2, cw1t, cb1, cw2, cb2, lng, lnb, nw1t, nb1, nw2t, nb2,
            w1tp, eb1, pOut);
        float* t;
        t = cIn; cIn = cOut; cOut = t;
        t = fIn; fIn = fOut; fOut = t;
        t = pIn; pIn = pOut; pOut = t;
    }

    final_kernel<<<NB * SL / 256, 256, 0, stream>>>(fIn, fw, fb, (float*)d_out);
}